// Round 1
// baseline (231.014 us; speedup 1.0000x reference)
//
#include <hip/hip_runtime.h>

#define GDIM 104
#define GG (GDIM * GDIM)
#define NA 3
#define NB 128
#define IMGF 832.0f
#define EPSF 1e-9f
#define PI_F 3.14159265358979323846f

__device__ __forceinline__ float sigmoidf_(float x) {
    return 1.0f / (1.0f + expf(-x));
}

// stable log-sigmoid, matches jax.nn.log_sigmoid semantics
__device__ __forceinline__ float logsigf_(float z) {
    return (z >= 0.0f) ? -log1pf(expf(-z)) : (z - log1pf(expf(z)));
}

__global__ __launch_bounds__(256) void det_main(const float* __restrict__ x,
                                                const float* __restrict__ tg,
                                                float* __restrict__ out,
                                                double* __restrict__ acc) {
    const float PR[NA]  = {20.0f / 8.0f, 50.0f / 8.0f, 110.0f / 8.0f};   // ANCHORS/stride
    const float AR[NA]  = {20.0f / IMGF, 50.0f / IMGF, 110.0f / IMGF};   // ANCHORS/IMAGE_SIZE

    int t = blockIdx.x * 256 + threadIdx.x;   // grid sized exactly: 128*10816 = 5408*256

    int b = t / GG;
    int r = t - b * GG;
    int i = r / GDIM;
    int j = r - i * GDIM;

    const float* tb = tg + (size_t)b * 4 * GG + r;
    float tx   = tb[0 * GG];
    float ty   = tb[1 * GG];
    float trr  = tb[2 * GG];
    float conf = tb[3 * GG];

    float tgx = ((float)j + tx) / (float)GDIM;
    float tgy = ((float)i + ty) / (float)GDIM;

    // riou per anchor, best = first max (strict > matches jnp.argmax)
    int best = 0;
    float bestv = -1.0f;
#pragma unroll
    for (int a = 0; a < NA; ++a) {
        float q = fminf(trr, AR[a]) / (fmaxf(trr, AR[a]) + EPSF);
        float ri = q * q;
        if (ri > bestv) { bestv = ri; best = a; }
    }

    float local_diou = 0.0f;
    float local_fl   = 0.0f;
    int   local_n    = 0;

    const float* xb = x + (size_t)b * (NA * 4) * GG + r;
    float4* outv = (float4*)out + (size_t)b * (NA * GG) + r;

#pragma unroll
    for (int a = 0; a < NA; ++a) {
        float p0 = xb[(a * 4 + 0) * GG];
        float p1 = xb[(a * 4 + 1) * GG];
        float p2 = xb[(a * 4 + 2) * GG];
        float p3 = xb[(a * 4 + 3) * GG];

        float bx = (sigmoidf_(p0) + (float)j) / (float)GDIM;
        float by = (sigmoidf_(p1) + (float)i) / (float)GDIM;
        float br = PR[a] * expf(p2) / (float)GDIM;
        float pc = sigmoidf_(p3);

        float4 o;
        o.x = bx * IMGF;
        o.y = by * IMGF;
        o.z = br * IMGF;
        o.w = pc;
        outv[(size_t)a * GG] = o;

        bool obj = (best == a) && (conf > 0.5f);

        if (obj) {
            local_n += 1;
            float dx = bx - tgx, dy = by - tgy;
            float d2 = dx * dx + dy * dy;
            float d  = sqrtf(d2 + EPSF);
            float r1 = br, r2 = trr;
            float rmin = fminf(r1, r2), rmax = fmaxf(r1, r2);
            float a1 = (d2 + r1 * r1 - r2 * r2) / (2.0f * d * r1 + EPSF);
            a1 = fminf(fmaxf(a1, -1.0f), 1.0f);
            float a2 = (d2 + r2 * r2 - r1 * r1) / (2.0f * d * r2 + EPSF);
            a2 = fminf(fmaxf(a2, -1.0f), 1.0f);
            float tt = (-d + r1 + r2) * (d + r1 - r2) * (d - r1 + r2) * (d + r1 + r2);
            tt = fmaxf(tt, 0.0f);
            float lens = r1 * r1 * acosf(a1) + r2 * r2 * acosf(a2) - 0.5f * sqrtf(tt);
            float inter = (d >= r1 + r2) ? 0.0f
                         : ((d <= rmax - rmin) ? PI_F * rmin * rmin : lens);
            float uni = PI_F * (r1 * r1 + r2 * r2) - inter;
            float iou = inter / (uni + EPSF);
            float s = d + r1 + r2;
            float pen = d2 / (s * s + EPSF);
            local_diou += 1.0f - iou + pen;
        }

        // focal loss (y = obj ? 1 : 0, gamma=2, alpha=0.25)
        float logp  = logsigf_(p3);
        float lognp = logsigf_(-p3);
        float fl;
        if (obj) {
            float u = 1.0f - pc;
            fl = -(0.25f * u * u * logp);
        } else {
            fl = -(0.75f * pc * pc * lognp);
        }
        local_fl += fl;
    }

    // wave64 reduce
#pragma unroll
    for (int off = 32; off > 0; off >>= 1) {
        local_diou += __shfl_down(local_diou, off);
        local_fl   += __shfl_down(local_fl, off);
        local_n    += __shfl_down(local_n, off);
    }

    __shared__ float sdiou[4];
    __shared__ float sfl[4];
    __shared__ int   sn[4];
    int wid  = threadIdx.x >> 6;
    int lane = threadIdx.x & 63;
    if (lane == 0) { sdiou[wid] = local_diou; sfl[wid] = local_fl; sn[wid] = local_n; }
    __syncthreads();
    if (threadIdx.x == 0) {
        float ds = 0.0f, fs = 0.0f;
        int ns = 0;
#pragma unroll
        for (int w = 0; w < 4; ++w) { ds += sdiou[w]; fs += sfl[w]; ns += sn[w]; }
        atomicAdd(&acc[0], (double)ds);
        atomicAdd(&acc[1], (double)fs);
        atomicAdd((unsigned long long*)&acc[2], (unsigned long long)ns);
    }
}

__global__ void det_finalize(const double* __restrict__ acc, float* __restrict__ out_scalar) {
    unsigned long long nobj_u = *(const unsigned long long*)&acc[2];
    double n = (double)nobj_u;
    if (n < 1.0) n = 1.0;
    double lb = acc[0] / n;
    double lc = acc[1] / (double)((size_t)NB * NA * GG);
    *out_scalar = (float)(lb + lc);
}

extern "C" void kernel_launch(void* const* d_in, const int* in_sizes, int n_in,
                              void* d_out, int out_size, void* d_ws, size_t ws_size,
                              hipStream_t stream) {
    const float* x  = (const float*)d_in[0];
    const float* tg = (const float*)d_in[1];
    float* out = (float*)d_out;
    double* acc = (double*)d_ws;

    hipMemsetAsync(d_ws, 0, 3 * sizeof(double), stream);

    int total = NB * GG;               // 1,384,448 = 5408 * 256 exactly
    det_main<<<total / 256, 256, 0, stream>>>(x, tg, out, acc);
    det_finalize<<<1, 1, 0, stream>>>(acc, out + (size_t)NB * NA * GG * 4);
}

// Round 2
// 215.367 us; speedup vs baseline: 1.0727x; 1.0727x over previous
//
#include <hip/hip_runtime.h>

#define GDIM 104
#define GG (GDIM * GDIM)
#define NA 3
#define NB 128
#define IMGF 832.0f
#define EPSF 1e-9f
#define PI_F 3.14159265358979323846f
#define INV_G (1.0f / 104.0f)

__device__ __forceinline__ float sigmoid_fast(float z) {
    return 1.0f / (1.0f + __expf(-z));
}

// acos minimax (Abramowitz-Stegun 4.4.45), |err| < 7e-5 rad
__device__ __forceinline__ float acos_fast(float x) {
    float ax = fabsf(x);
    float t = sqrtf(fmaxf(1.0f - ax, 0.0f));
    float p = fmaf(-0.0187293f, ax, 0.0742610f);
    p = fmaf(p, ax, -0.2121144f);
    p = fmaf(p, ax, 1.5707288f);
    float r = t * p;
    return (x < 0.0f) ? (PI_F - r) : r;
}

__global__ __launch_bounds__(256) void det_main(const float* __restrict__ x,
                                                const float* __restrict__ tg,
                                                float* __restrict__ out,
                                                double* __restrict__ acc) {
    const float PR[NA] = {20.0f / 8.0f, 50.0f / 8.0f, 110.0f / 8.0f};   // ANCHORS/stride
    const float AR[NA] = {20.0f / IMGF, 50.0f / IMGF, 110.0f / IMGF};   // ANCHORS/IMAGE_SIZE

    int t = blockIdx.x * 256 + threadIdx.x;   // grid exact: 128*10816 = 5408*256

    int b = t / GG;
    int r = t - b * GG;
    int i = r / GDIM;
    int j = r - i * GDIM;

    const float* tb = tg + (size_t)b * 4 * GG + r;
    float tx   = tb[0 * GG];
    float ty   = tb[1 * GG];
    float trr  = tb[2 * GG];
    float conf = tb[3 * GG];

    float fj = (float)j, fi = (float)i;
    float tgx = (fj + tx) * INV_G;
    float tgy = (fi + ty) * INV_G;

    // best anchor = argmax riou (first-max tie rule via strict >)
    int best = 0;
    float bestv = -1.0f;
#pragma unroll
    for (int a = 0; a < NA; ++a) {
        float q = fminf(trr, AR[a]) / (fmaxf(trr, AR[a]) + EPSF);
        float ri = q * q;
        if (ri > bestv) { bestv = ri; best = a; }
    }

    bool posconf = (conf > 0.5f);
    float local_fl = 0.0f;
    float sbx = 0.0f, sby = 0.0f, sbr = 0.0f;

    const float* xb = x + (size_t)b * (NA * 4) * GG + r;
    float4* outv = (float4*)out + (size_t)b * (NA * GG) + r;

#pragma unroll
    for (int a = 0; a < NA; ++a) {
        float p0 = xb[(a * 4 + 0) * GG];
        float p1 = xb[(a * 4 + 1) * GG];
        float p2 = xb[(a * 4 + 2) * GG];
        float p3 = xb[(a * 4 + 3) * GG];

        float sx = sigmoid_fast(p0);
        float sy = sigmoid_fast(p1);
        float ex = __expf(p2);

        float bx = (sx + fj) * INV_G;
        float by = (sy + fi) * INV_G;
        float br = PR[a] * ex * INV_G;

        // p3: shared exp for sigmoid + focal
        float e   = __expf(-p3);
        float pc  = 1.0f / (1.0f + e);
        float l1e = __logf(1.0f + e);          // = -log_sigmoid(p3)
        // logp = -l1e ; lognp = -(p3 + l1e)

        float4 o;
        o.x = (sx + fj) * 8.0f;
        o.y = (sy + fi) * 8.0f;
        o.z = br * IMGF;
        o.w = pc;
        outv[(size_t)a * GG] = o;

        bool obj = posconf && (a == best);

        float u = 1.0f - pc;
        float fl_pos = 0.25f * u * u * l1e;
        float fl_neg = 0.75f * pc * pc * (p3 + l1e);
        local_fl += obj ? fl_pos : fl_neg;

        // keep best anchor's decoded box for the single DIoU eval
        sbx = (a == best) ? bx : sbx;
        sby = (a == best) ? by : sby;
        sbr = (a == best) ? br : sbr;
    }

    float local_diou = 0.0f;
    int   local_n    = 0;
    if (posconf) {
        local_n = 1;
        float dx = sbx - tgx, dy = sby - tgy;
        float d2 = dx * dx + dy * dy;
        float d  = sqrtf(d2 + EPSF);
        float r1 = sbr, r2 = trr;
        float rmin = fminf(r1, r2), rmax = fmaxf(r1, r2);
        float a1 = (d2 + r1 * r1 - r2 * r2) / (2.0f * d * r1 + EPSF);
        a1 = fminf(fmaxf(a1, -1.0f), 1.0f);
        float a2 = (d2 + r2 * r2 - r1 * r1) / (2.0f * d * r2 + EPSF);
        a2 = fminf(fmaxf(a2, -1.0f), 1.0f);
        float tt = (-d + r1 + r2) * (d + r1 - r2) * (d - r1 + r2) * (d + r1 + r2);
        tt = fmaxf(tt, 0.0f);
        float lens = r1 * r1 * acos_fast(a1) + r2 * r2 * acos_fast(a2) - 0.5f * sqrtf(tt);
        float inter = (d >= r1 + r2) ? 0.0f
                     : ((d <= rmax - rmin) ? PI_F * rmin * rmin : lens);
        float uni = PI_F * (r1 * r1 + r2 * r2) - inter;
        float iou = inter / (uni + EPSF);
        float s = d + r1 + r2;
        float pen = d2 / (s * s + EPSF);
        local_diou = 1.0f - iou + pen;
    }

    // wave64 reduce
#pragma unroll
    for (int off = 32; off > 0; off >>= 1) {
        local_diou += __shfl_down(local_diou, off);
        local_fl   += __shfl_down(local_fl, off);
        local_n    += __shfl_down(local_n, off);
    }

    __shared__ float sdiou[4];
    __shared__ float sfl[4];
    __shared__ int   sn[4];
    int wid  = threadIdx.x >> 6;
    int lane = threadIdx.x & 63;
    if (lane == 0) { sdiou[wid] = local_diou; sfl[wid] = local_fl; sn[wid] = local_n; }
    __syncthreads();
    if (threadIdx.x == 0) {
        float ds = 0.0f, fs = 0.0f;
        int ns = 0;
#pragma unroll
        for (int w = 0; w < 4; ++w) { ds += sdiou[w]; fs += sfl[w]; ns += sn[w]; }
        atomicAdd(&acc[0], (double)ds);
        atomicAdd(&acc[1], (double)fs);
        atomicAdd((unsigned long long*)&acc[2], (unsigned long long)ns);
    }
}

__global__ void det_finalize(const double* __restrict__ acc, float* __restrict__ out_scalar) {
    unsigned long long nobj_u = *(const unsigned long long*)&acc[2];
    double n = (double)nobj_u;
    if (n < 1.0) n = 1.0;
    double lb = acc[0] / n;
    double lc = acc[1] / (double)((size_t)NB * NA * GG);
    *out_scalar = (float)(lb + lc);
}

extern "C" void kernel_launch(void* const* d_in, const int* in_sizes, int n_in,
                              void* d_out, int out_size, void* d_ws, size_t ws_size,
                              hipStream_t stream) {
    const float* x  = (const float*)d_in[0];
    const float* tg = (const float*)d_in[1];
    float* out = (float*)d_out;
    double* acc = (double*)d_ws;

    hipMemsetAsync(d_ws, 0, 3 * sizeof(double), stream);

    int total = NB * GG;               // 1,384,448 = 5408 * 256
    det_main<<<total / 256, 256, 0, stream>>>(x, tg, out, acc);
    det_finalize<<<1, 1, 0, stream>>>(acc, out + (size_t)NB * NA * GG * 4);
}

// Round 3
// 52.621 us; speedup vs baseline: 4.3902x; 4.0928x over previous
//
#include <hip/hip_runtime.h>

#define GDIM 104
#define GG (GDIM * GDIM)          // 10816
#define GG4 (GG / 4)              // 2704
#define NA 3
#define NB 128
#define NBLK 1352                 // NB*GG4/256
#define IMGF 832.0f
#define EPSF 1e-9f
#define PI_F 3.14159265358979323846f
#define INV_G (1.0f / 104.0f)

__device__ __forceinline__ float sigmoid_fast(float z) {
    return 1.0f / (1.0f + __expf(-z));
}

// acos minimax (Abramowitz-Stegun 4.4.45), |err| < 7e-5 rad
__device__ __forceinline__ float acos_fast(float x) {
    float ax = fabsf(x);
    float t = sqrtf(fmaxf(1.0f - ax, 0.0f));
    float p = fmaf(-0.0187293f, ax, 0.0742610f);
    p = fmaf(p, ax, -0.2121144f);
    p = fmaf(p, ax, 1.5707288f);
    float r = t * p;
    return (x < 0.0f) ? (PI_F - r) : r;
}

__device__ __forceinline__ float f4c(const float4& v, int c) {
    return c == 0 ? v.x : c == 1 ? v.y : c == 2 ? v.z : v.w;
}

__global__ __launch_bounds__(256) void det_main(const float4* __restrict__ x4,
                                                const float4* __restrict__ tg4,
                                                float4* __restrict__ out4,
                                                float* __restrict__ ws) {
    const float PR[NA] = {20.0f / 8.0f, 50.0f / 8.0f, 110.0f / 8.0f};   // ANCHORS/stride
    const float AR[NA] = {20.0f / IMGF, 50.0f / IMGF, 110.0f / IMGF};   // ANCHORS/IMAGE_SIZE

    int t = blockIdx.x * 256 + threadIdx.x;    // grid exact: 128*2704 = 1352*256
    int b  = t / GG4;
    int rq = t - b * GG4;
    int i  = rq / (GDIM / 4);                  // /26
    int jq = rq - i * (GDIM / 4);
    float fi  = (float)i;
    float fj0 = (float)(4 * jq);

    // targets: 4 planes, one float4 (=4 cells) each — issue all loads up front
    const float4* tb = tg4 + (size_t)b * (4 * GG4) + rq;
    float4 vtx = tb[0 * GG4];
    float4 vty = tb[1 * GG4];
    float4 vtr = tb[2 * GG4];
    float4 vcf = tb[3 * GG4];

    // x: 12 planes, one float4 each
    const float4* xb = x4 + (size_t)b * (12 * GG4) + rq;
    float4 px[12];
#pragma unroll
    for (int k = 0; k < 12; ++k) px[k] = xb[(size_t)k * GG4];

    size_t obase = (size_t)b * (NA * GG) + 4 * (size_t)rq;

    float l_fl = 0.0f, l_di = 0.0f;
    int   l_n  = 0;

#pragma unroll
    for (int c = 0; c < 4; ++c) {
        float tx  = f4c(vtx, c);
        float ty  = f4c(vty, c);
        float trr = f4c(vtr, c);
        float cf  = f4c(vcf, c);
        float fj  = fj0 + (float)c;
        float tgx = (fj + tx) * INV_G;
        float tgy = (fi + ty) * INV_G;

        // best anchor = argmax riou (first-max tie rule via strict >)
        int best = 0;
        float bestv = -1.0f;
#pragma unroll
        for (int a = 0; a < NA; ++a) {
            float q = fminf(trr, AR[a]) / (fmaxf(trr, AR[a]) + EPSF);
            float ri = q * q;
            if (ri > bestv) { bestv = ri; best = a; }
        }
        bool pos = (cf > 0.5f);

        float sbx = 0.0f, sby = 0.0f, sbr = 0.0f;
#pragma unroll
        for (int a = 0; a < NA; ++a) {
            float p0 = f4c(px[a * 4 + 0], c);
            float p1 = f4c(px[a * 4 + 1], c);
            float p2 = f4c(px[a * 4 + 2], c);
            float p3 = f4c(px[a * 4 + 3], c);

            float sx = sigmoid_fast(p0);
            float sy = sigmoid_fast(p1);
            float br = PR[a] * __expf(p2) * INV_G;

            float e   = __expf(-p3);
            float pc  = 1.0f / (1.0f + e);
            float l1e = __logf(1.0f + e);     // = -log_sigmoid(p3)

            float4 o;
            o.x = (sx + fj) * 8.0f;
            o.y = (sy + fi) * 8.0f;
            o.z = br * IMGF;
            o.w = pc;
            out4[obase + (size_t)a * GG + c] = o;

            bool obj = pos && (a == best);
            float u = 1.0f - pc;
            l_fl += obj ? 0.25f * u * u * l1e : 0.75f * pc * pc * (p3 + l1e);

            if (a == best) { sbx = (sx + fj) * INV_G; sby = (sy + fi) * INV_G; sbr = br; }
        }

        if (pos) {
            l_n += 1;
            float dx = sbx - tgx, dy = sby - tgy;
            float d2 = dx * dx + dy * dy;
            float d  = sqrtf(d2 + EPSF);
            float r1 = sbr, r2 = trr;
            float rmin = fminf(r1, r2), rmax = fmaxf(r1, r2);
            float a1 = (d2 + r1 * r1 - r2 * r2) / (2.0f * d * r1 + EPSF);
            a1 = fminf(fmaxf(a1, -1.0f), 1.0f);
            float a2 = (d2 + r2 * r2 - r1 * r1) / (2.0f * d * r2 + EPSF);
            a2 = fminf(fmaxf(a2, -1.0f), 1.0f);
            float tt = (-d + r1 + r2) * (d + r1 - r2) * (d - r1 + r2) * (d + r1 + r2);
            tt = fmaxf(tt, 0.0f);
            float lens = r1 * r1 * acos_fast(a1) + r2 * r2 * acos_fast(a2) - 0.5f * sqrtf(tt);
            float inter = (d >= r1 + r2) ? 0.0f
                         : ((d <= rmax - rmin) ? PI_F * rmin * rmin : lens);
            float uni = PI_F * (r1 * r1 + r2 * r2) - inter;
            float iou = inter / (uni + EPSF);
            float s = d + r1 + r2;
            float pen = d2 / (s * s + EPSF);
            l_di += 1.0f - iou + pen;
        }
    }

    // wave64 reduce
    float l_nf = (float)l_n;
#pragma unroll
    for (int off = 32; off > 0; off >>= 1) {
        l_di += __shfl_down(l_di, off);
        l_fl += __shfl_down(l_fl, off);
        l_nf += __shfl_down(l_nf, off);
    }

    __shared__ float sdiou[4], sfl[4], sn[4];
    int wid  = threadIdx.x >> 6;
    int lane = threadIdx.x & 63;
    if (lane == 0) { sdiou[wid] = l_di; sfl[wid] = l_fl; sn[wid] = l_nf; }
    __syncthreads();
    if (threadIdx.x == 0) {
        float ds = 0.0f, fs = 0.0f, ns = 0.0f;
#pragma unroll
        for (int w = 0; w < 4; ++w) { ds += sdiou[w]; fs += sfl[w]; ns += sn[w]; }
        ws[blockIdx.x]            = ds;
        ws[NBLK + blockIdx.x]     = fs;
        ws[2 * NBLK + blockIdx.x] = ns;
    }
}

__global__ __launch_bounds__(256) void det_finalize(const float* __restrict__ ws,
                                                    float* __restrict__ out_scalar) {
    float ds = 0.0f, fs = 0.0f, ns = 0.0f;
    for (int k = threadIdx.x; k < NBLK; k += 256) {
        ds += ws[k];
        fs += ws[NBLK + k];
        ns += ws[2 * NBLK + k];
    }
#pragma unroll
    for (int off = 32; off > 0; off >>= 1) {
        ds += __shfl_down(ds, off);
        fs += __shfl_down(fs, off);
        ns += __shfl_down(ns, off);
    }
    __shared__ float s0[4], s1[4], s2[4];
    int wid  = threadIdx.x >> 6;
    int lane = threadIdx.x & 63;
    if (lane == 0) { s0[wid] = ds; s1[wid] = fs; s2[wid] = ns; }
    __syncthreads();
    if (threadIdx.x == 0) {
        float D = 0.0f, F = 0.0f, N = 0.0f;
#pragma unroll
        for (int w = 0; w < 4; ++w) { D += s0[w]; F += s1[w]; N += s2[w]; }
        double n = (N < 1.0f) ? 1.0 : (double)N;
        out_scalar[0] = (float)((double)D / n + (double)F / (double)((size_t)NB * NA * GG));
    }
}

extern "C" void kernel_launch(void* const* d_in, const int* in_sizes, int n_in,
                              void* d_out, int out_size, void* d_ws, size_t ws_size,
                              hipStream_t stream) {
    const float4* x4  = (const float4*)d_in[0];
    const float4* tg4 = (const float4*)d_in[1];
    float* out = (float*)d_out;
    float* ws  = (float*)d_ws;

    det_main<<<NBLK, 256, 0, stream>>>(x4, tg4, (float4*)out, ws);
    det_finalize<<<1, 256, 0, stream>>>(ws, out + (size_t)NB * NA * GG * 4);
}

// Round 4
// 35.986 us; speedup vs baseline: 6.4196x; 1.4623x over previous
//
#include <hip/hip_runtime.h>

#define GDIM 104
#define GG (GDIM * GDIM)          // 10816
#define NA 3
#define NB 128
#define NBLK 1352                 // NB*GG / 1024
#define IMGF 832.0f
#define EPSF 1e-9f
#define PI_F 3.14159265358979323846f
#define INV_G (1.0f / 104.0f)

__device__ __forceinline__ float sigmoid_fast(float z) {
    return 1.0f / (1.0f + __expf(-z));
}

// acos minimax (Abramowitz-Stegun 4.4.45), |err| < 7e-5 rad
__device__ __forceinline__ float acos_fast(float x) {
    float ax = fabsf(x);
    float t = sqrtf(fmaxf(1.0f - ax, 0.0f));
    float p = fmaf(-0.0187293f, ax, 0.0742610f);
    p = fmaf(p, ax, -0.2121144f);
    p = fmaf(p, ax, 1.5707288f);
    float r = t * p;
    return (x < 0.0f) ? (PI_F - r) : r;
}

__global__ __launch_bounds__(256) void det_main(const float* __restrict__ x,
                                                const float* __restrict__ tg,
                                                float4* __restrict__ out4,
                                                float* __restrict__ ws) {
    const float PR[NA] = {20.0f / 8.0f, 50.0f / 8.0f, 110.0f / 8.0f};   // ANCHORS/stride
    const float AR[NA] = {20.0f / IMGF, 50.0f / IMGF, 110.0f / IMGF};   // ANCHORS/IMAGE_SIZE

    int base = blockIdx.x * 1024 + threadIdx.x;   // thread owns cells base + c*256

    // ---- issue ALL loads up front (64 coalesced scalar loads, lane-contiguous) ----
    int bb[4], rr[4];
    float vt[4][4];     // targets [c][plane]
    float vp[4][12];    // x       [c][plane]
#pragma unroll
    for (int c = 0; c < 4; ++c) {
        int gc = base + c * 256;
        int b = gc / GG;
        int r = gc - b * GG;
        bb[c] = b; rr[c] = r;
        const float* tb = tg + (size_t)b * (4 * GG) + r;
#pragma unroll
        for (int p = 0; p < 4; ++p) vt[c][p] = tb[(size_t)p * GG];
        const float* xb = x + (size_t)b * (12 * GG) + r;
#pragma unroll
        for (int p = 0; p < 12; ++p) vp[c][p] = xb[(size_t)p * GG];
    }

    float l_fl = 0.0f, l_di = 0.0f;
    int   l_n  = 0;

#pragma unroll
    for (int c = 0; c < 4; ++c) {
        int b = bb[c], r = rr[c];
        int i = r / GDIM;
        int j = r - i * GDIM;
        float fi = (float)i, fj = (float)j;

        float tx  = vt[c][0];
        float ty  = vt[c][1];
        float trr = vt[c][2];
        float cf  = vt[c][3];
        float tgx = (fj + tx) * INV_G;
        float tgy = (fi + ty) * INV_G;

        // best anchor = argmax riou (first-max tie rule via strict >)
        int best = 0;
        float bestv = -1.0f;
#pragma unroll
        for (int a = 0; a < NA; ++a) {
            float q = fminf(trr, AR[a]) / (fmaxf(trr, AR[a]) + EPSF);
            float ri = q * q;
            if (ri > bestv) { bestv = ri; best = a; }
        }
        bool pos = (cf > 0.5f);

        size_t obase = (size_t)b * (NA * GG) + r;
        float sbx = 0.0f, sby = 0.0f, sbr = 0.0f;
#pragma unroll
        for (int a = 0; a < NA; ++a) {
            float p0 = vp[c][a * 4 + 0];
            float p1 = vp[c][a * 4 + 1];
            float p2 = vp[c][a * 4 + 2];
            float p3 = vp[c][a * 4 + 3];

            float sx = sigmoid_fast(p0);
            float sy = sigmoid_fast(p1);
            float br = PR[a] * __expf(p2) * INV_G;

            float e   = __expf(-p3);
            float pc  = 1.0f / (1.0f + e);
            float l1e = __logf(1.0f + e);     // = -log_sigmoid(p3)

            float4 o;
            o.x = (sx + fj) * 8.0f;
            o.y = (sy + fi) * 8.0f;
            o.z = br * IMGF;
            o.w = pc;
            out4[obase + (size_t)a * GG] = o;   // lane-contiguous 16B stores

            bool obj = pos && (a == best);
            float u = 1.0f - pc;
            l_fl += obj ? 0.25f * u * u * l1e : 0.75f * pc * pc * (p3 + l1e);

            if (a == best) { sbx = (sx + fj) * INV_G; sby = (sy + fi) * INV_G; sbr = br; }
        }

        if (pos) {
            l_n += 1;
            float dx = sbx - tgx, dy = sby - tgy;
            float d2 = dx * dx + dy * dy;
            float d  = sqrtf(d2 + EPSF);
            float r1 = sbr, r2 = trr;
            float rmin = fminf(r1, r2), rmax = fmaxf(r1, r2);
            float a1 = (d2 + r1 * r1 - r2 * r2) / (2.0f * d * r1 + EPSF);
            a1 = fminf(fmaxf(a1, -1.0f), 1.0f);
            float a2 = (d2 + r2 * r2 - r1 * r1) / (2.0f * d * r2 + EPSF);
            a2 = fminf(fmaxf(a2, -1.0f), 1.0f);
            float tt = (-d + r1 + r2) * (d + r1 - r2) * (d - r1 + r2) * (d + r1 + r2);
            tt = fmaxf(tt, 0.0f);
            float lens = r1 * r1 * acos_fast(a1) + r2 * r2 * acos_fast(a2) - 0.5f * sqrtf(tt);
            float inter = (d >= r1 + r2) ? 0.0f
                         : ((d <= rmax - rmin) ? PI_F * rmin * rmin : lens);
            float uni = PI_F * (r1 * r1 + r2 * r2) - inter;
            float iou = inter / (uni + EPSF);
            float s = d + r1 + r2;
            float pen = d2 / (s * s + EPSF);
            l_di += 1.0f - iou + pen;
        }
    }

    // wave64 reduce
    float l_nf = (float)l_n;
#pragma unroll
    for (int off = 32; off > 0; off >>= 1) {
        l_di += __shfl_down(l_di, off);
        l_fl += __shfl_down(l_fl, off);
        l_nf += __shfl_down(l_nf, off);
    }

    __shared__ float sdiou[4], sfl[4], sn[4];
    int wid  = threadIdx.x >> 6;
    int lane = threadIdx.x & 63;
    if (lane == 0) { sdiou[wid] = l_di; sfl[wid] = l_fl; sn[wid] = l_nf; }
    __syncthreads();
    if (threadIdx.x == 0) {
        float ds = 0.0f, fs = 0.0f, ns = 0.0f;
#pragma unroll
        for (int w = 0; w < 4; ++w) { ds += sdiou[w]; fs += sfl[w]; ns += sn[w]; }
        ws[blockIdx.x]            = ds;
        ws[NBLK + blockIdx.x]     = fs;
        ws[2 * NBLK + blockIdx.x] = ns;
    }
}

__global__ __launch_bounds__(256) void det_finalize(const float* __restrict__ ws,
                                                    float* __restrict__ out_scalar) {
    float ds = 0.0f, fs = 0.0f, ns = 0.0f;
    for (int k = threadIdx.x; k < NBLK; k += 256) {
        ds += ws[k];
        fs += ws[NBLK + k];
        ns += ws[2 * NBLK + k];
    }
#pragma unroll
    for (int off = 32; off > 0; off >>= 1) {
        ds += __shfl_down(ds, off);
        fs += __shfl_down(fs, off);
        ns += __shfl_down(ns, off);
    }
    __shared__ float s0[4], s1[4], s2[4];
    int wid  = threadIdx.x >> 6;
    int lane = threadIdx.x & 63;
    if (lane == 0) { s0[wid] = ds; s1[wid] = fs; s2[wid] = ns; }
    __syncthreads();
    if (threadIdx.x == 0) {
        float D = 0.0f, F = 0.0f, N = 0.0f;
#pragma unroll
        for (int w = 0; w < 4; ++w) { D += s0[w]; F += s1[w]; N += s2[w]; }
        double n = (N < 1.0f) ? 1.0 : (double)N;
        out_scalar[0] = (float)((double)D / n + (double)F / (double)((size_t)NB * NA * GG));
    }
}

extern "C" void kernel_launch(void* const* d_in, const int* in_sizes, int n_in,
                              void* d_out, int out_size, void* d_ws, size_t ws_size,
                              hipStream_t stream) {
    const float* x  = (const float*)d_in[0];
    const float* tg = (const float*)d_in[1];
    float* out = (float*)d_out;
    float* ws  = (float*)d_ws;

    det_main<<<NBLK, 256, 0, stream>>>(x, tg, (float4*)out, ws);
    det_finalize<<<1, 256, 0, stream>>>(ws, out + (size_t)NB * NA * GG * 4);
}